// Round 1
// baseline (30.430 us; speedup 1.0000x reference)
//
#include <hip/hip_runtime.h>

// Median blur 3x3, zero padding, lower median (== true median for 9 elems).
// x: (16, 3, 512, 512) float32 contiguous. Out same shape/dtype.

__device__ __forceinline__ void s2(float& a, float& b) {
    float t = fminf(a, b);
    b = fmaxf(a, b);
    a = t;
}

// Paeth 19-exchange median-of-9 network; result in p4.
__device__ __forceinline__ float med9(float p0, float p1, float p2,
                                      float p3, float p4, float p5,
                                      float p6, float p7, float p8) {
    s2(p1, p2); s2(p4, p5); s2(p7, p8);
    s2(p0, p1); s2(p3, p4); s2(p6, p7);
    s2(p1, p2); s2(p4, p5); s2(p7, p8);
    s2(p0, p3); s2(p5, p8); s2(p4, p7);
    s2(p3, p6); s2(p1, p4); s2(p2, p5);
    s2(p4, p7); s2(p4, p2); s2(p6, p4);
    s2(p4, p2);
    return p4;
}

__global__ __launch_bounds__(256) void median_blur_kernel(
        const float* __restrict__ x, float* __restrict__ out) {
    constexpr int W = 512, H = 512, W4 = W / 4;  // 128 groups/row
    int gid = blockIdx.x * blockDim.x + threadIdx.x;
    // gid -> (plane, h, w-group); per-plane groups = H*W4 = 65536
    int w4 = gid & (W4 - 1);
    int h  = (gid >> 7) & (H - 1);
    int bc = gid >> 16;

    const float* plane = x + (size_t)bc * H * W;
    int c0 = w4 * 4;

    float r[3][6];
#pragma unroll
    for (int i = 0; i < 3; ++i) {
        int rr = h - 1 + i;
        if (rr >= 0 && rr < H) {
            const float* p = plane + (size_t)rr * W + c0;
            float4 v = *reinterpret_cast<const float4*>(p);
            r[i][1] = v.x; r[i][2] = v.y; r[i][3] = v.z; r[i][4] = v.w;
            r[i][0] = (c0 > 0)      ? p[-1] : 0.0f;
            r[i][5] = (c0 + 4 < W)  ? p[4]  : 0.0f;
        } else {
            r[i][0] = r[i][1] = r[i][2] = 0.0f;
            r[i][3] = r[i][4] = r[i][5] = 0.0f;
        }
    }

    float4 o;
    o.x = med9(r[0][0], r[0][1], r[0][2],
               r[1][0], r[1][1], r[1][2],
               r[2][0], r[2][1], r[2][2]);
    o.y = med9(r[0][1], r[0][2], r[0][3],
               r[1][1], r[1][2], r[1][3],
               r[2][1], r[2][2], r[2][3]);
    o.z = med9(r[0][2], r[0][3], r[0][4],
               r[1][2], r[1][3], r[1][4],
               r[2][2], r[2][3], r[2][4]);
    o.w = med9(r[0][3], r[0][4], r[0][5],
               r[1][3], r[1][4], r[1][5],
               r[2][3], r[2][4], r[2][5]);

    float* po = out + ((size_t)bc * H + h) * W + c0;
    *reinterpret_cast<float4*>(po) = o;
}

extern "C" void kernel_launch(void* const* d_in, const int* in_sizes, int n_in,
                              void* d_out, int out_size, void* d_ws, size_t ws_size,
                              hipStream_t stream) {
    const float* x = (const float*)d_in[0];
    float* out = (float*)d_out;
    // 16*3 planes * 512 rows * 128 groups = 3,145,728 threads
    constexpr int threads = 256;
    constexpr int total = 16 * 3 * 512 * (512 / 4);
    median_blur_kernel<<<total / threads, threads, 0, stream>>>(x, out);
}

// Round 2
// 26.364 us; speedup vs baseline: 1.1542x; 1.1542x over previous
//
#include <hip/hip_runtime.h>

// Median blur 3x3, zero padding, lower median (== true median for 9 elems).
// x: (16, 3, 512, 512) float32 contiguous. Out same shape/dtype.
//
// R2: vertical register blocking (8 output rows / thread, rolling 3-row
// window) to cut the 3x vertical HBM read amplification to 1.25x, plus
// column-sort median (shared sort3 per column across 4 horizontal outputs).

__device__ __forceinline__ void s2(float& a, float& b) {
    float t = fminf(a, b);
    b = fmaxf(a, b);
    a = t;
}

__device__ __forceinline__ float max3(float a, float b, float c) {
    return fmaxf(fmaxf(a, b), c);
}
__device__ __forceinline__ float min3(float a, float b, float c) {
    return fminf(fminf(a, b), c);
}
__device__ __forceinline__ float med3(float a, float b, float c) {
    return fmaxf(fminf(a, b), fminf(fmaxf(a, b), c));
}

__device__ __forceinline__ void load_row(float (&d)[6], const float* __restrict__ plane,
                                         int rr, int c0) {
    if (rr >= 0 && rr < 512) {
        const float* p = plane + rr * 512 + c0;
        float4 v = *reinterpret_cast<const float4*>(p);
        d[1] = v.x; d[2] = v.y; d[3] = v.z; d[4] = v.w;
        d[0] = (c0 > 0)       ? p[-1] : 0.0f;
        d[5] = (c0 + 4 < 512) ? p[4]  : 0.0f;
    } else {
        d[0] = d[1] = d[2] = 0.0f;
        d[3] = d[4] = d[5] = 0.0f;
    }
}

constexpr int ROWS = 8;  // output rows per thread

__global__ __launch_bounds__(256) void median_blur_kernel(
        const float* __restrict__ x, float* __restrict__ out) {
    constexpr int W = 512, H = 512, W4 = W / 4;   // 128 groups/row
    constexpr int RB = H / ROWS;                  // 64 row-blocks

    // Bijective XCD-chunked swizzle (gridDim.x == 1536, divisible by 8):
    // consecutive row-blocks of a plane land on the same XCD's L2.
    int nwg = gridDim.x;
    int cpx = nwg >> 3;
    int bid = (blockIdx.x & 7) * cpx + (blockIdx.x >> 3);

    int gid = bid * blockDim.x + threadIdx.x;
    int w4 = gid & (W4 - 1);
    int rb = (gid >> 7) & (RB - 1);
    int bc = gid >> 13;

    const float* plane = x + (size_t)bc * H * W;
    float* oplane = out + (size_t)bc * H * W;
    int c0 = w4 * 4;
    int h0 = rb * ROWS;

    float r[3][6];
    load_row(r[0], plane, h0 - 1, c0);
    load_row(r[1], plane, h0,     c0);

#pragma unroll
    for (int i = 0; i < ROWS; ++i) {
        load_row(r[(i + 2) % 3], plane, h0 + i + 1, c0);

        const float (&ra)[6] = r[(i + 0) % 3];
        const float (&rbv)[6] = r[(i + 1) % 3];
        const float (&rc)[6] = r[(i + 2) % 3];

        // Sort the 6 columns of 3 (lo <= mi <= hi), shared across 4 outputs.
        float lo[6], mi[6], hi[6];
#pragma unroll
        for (int j = 0; j < 6; ++j) {
            float a = ra[j], b = rbv[j], c = rc[j];
            s2(b, c); s2(a, c); s2(a, b);
            lo[j] = a; mi[j] = b; hi[j] = c;
        }

        float4 o;
        o.x = med3(max3(lo[0], lo[1], lo[2]),
                   med3(mi[0], mi[1], mi[2]),
                   min3(hi[0], hi[1], hi[2]));
        o.y = med3(max3(lo[1], lo[2], lo[3]),
                   med3(mi[1], mi[2], mi[3]),
                   min3(hi[1], hi[2], hi[3]));
        o.z = med3(max3(lo[2], lo[3], lo[4]),
                   med3(mi[2], mi[3], mi[4]),
                   min3(hi[2], hi[3], hi[4]));
        o.w = med3(max3(lo[3], lo[4], lo[5]),
                   med3(mi[3], mi[4], mi[5]),
                   min3(hi[3], hi[4], hi[5]));

        float* po = oplane + (size_t)(h0 + i) * W + c0;
        *reinterpret_cast<float4*>(po) = o;
    }
}

extern "C" void kernel_launch(void* const* d_in, const int* in_sizes, int n_in,
                              void* d_out, int out_size, void* d_ws, size_t ws_size,
                              hipStream_t stream) {
    const float* x = (const float*)d_in[0];
    float* out = (float*)d_out;
    // 16*3 planes * 64 row-blocks * 128 groups = 393,216 threads -> 1536 blocks
    constexpr int threads = 256;
    constexpr int total = 16 * 3 * (512 / ROWS) * (512 / 4);
    median_blur_kernel<<<total / threads, threads, 0, stream>>>(x, out);
}

// Round 4
// 21.457 us; speedup vs baseline: 1.4182x; 1.2287x over previous
//
#include <hip/hip_runtime.h>

// Median blur 3x3, zero padding, lower median (== true median for 9 elems).
// x: (16, 3, 512, 512) float32 contiguous. Out same shape/dtype.
//
// R4: R3 with the nontemporal store fixed (native ext_vector_type instead
// of HIP's float4 class). Full upfront preload of all 10 halo rows per
// thread, then 8 iterations of pure VALU column-sort median + NT stores.

typedef float vf4 __attribute__((ext_vector_type(4)));

__device__ __forceinline__ void s2(float& a, float& b) {
    float t = fminf(a, b);
    b = fmaxf(a, b);
    a = t;
}

__device__ __forceinline__ float max3(float a, float b, float c) {
    return fmaxf(fmaxf(a, b), c);
}
__device__ __forceinline__ float min3(float a, float b, float c) {
    return fminf(fminf(a, b), c);
}
__device__ __forceinline__ float med3(float a, float b, float c) {
    return fmaxf(fminf(a, b), fminf(fmaxf(a, b), c));
}

constexpr int ROWS = 8;  // output rows per thread

__global__ __launch_bounds__(256) void median_blur_kernel(
        const float* __restrict__ x, float* __restrict__ out) {
    constexpr int W = 512, H = 512, W4 = W / 4;   // 128 groups/row
    constexpr int RB = H / ROWS;                  // 64 row-blocks

    // Bijective XCD-chunked swizzle (gridDim.x == 1536, divisible by 8).
    int nwg = gridDim.x;
    int cpx = nwg >> 3;
    int bid = (blockIdx.x & 7) * cpx + (blockIdx.x >> 3);

    int gid = bid * blockDim.x + threadIdx.x;
    int w4 = gid & (W4 - 1);
    int rb = (gid >> 7) & (RB - 1);
    int bc = gid >> 13;

    const float* plane = x + (size_t)bc * H * W;
    float* oplane = out + (size_t)bc * H * W;
    int c0 = w4 * 4;
    int h0 = rb * ROWS;

    // Preload all ROWS+2 halo rows; all loads issue before any use.
    float r[ROWS + 2][6];
#pragma unroll
    for (int i = 0; i < ROWS + 2; ++i) {
        int rr = h0 - 1 + i;
        if (rr >= 0 && rr < H) {
            const float* p = plane + rr * W + c0;
            vf4 v = *reinterpret_cast<const vf4*>(p);
            r[i][1] = v.x; r[i][2] = v.y; r[i][3] = v.z; r[i][4] = v.w;
            r[i][0] = (c0 > 0)     ? p[-1] : 0.0f;
            r[i][5] = (c0 + 4 < W) ? p[4]  : 0.0f;
        } else {
            r[i][0] = r[i][1] = r[i][2] = 0.0f;
            r[i][3] = r[i][4] = r[i][5] = 0.0f;
        }
    }

#pragma unroll
    for (int i = 0; i < ROWS; ++i) {
        // Sort the 6 columns of 3 (lo <= mi <= hi), shared across 4 outputs.
        float lo[6], mi[6], hi[6];
#pragma unroll
        for (int j = 0; j < 6; ++j) {
            float a = r[i][j], b = r[i + 1][j], c = r[i + 2][j];
            s2(b, c); s2(a, c); s2(a, b);
            lo[j] = a; mi[j] = b; hi[j] = c;
        }

        vf4 o;
        o.x = med3(max3(lo[0], lo[1], lo[2]),
                   med3(mi[0], mi[1], mi[2]),
                   min3(hi[0], hi[1], hi[2]));
        o.y = med3(max3(lo[1], lo[2], lo[3]),
                   med3(mi[1], mi[2], mi[3]),
                   min3(hi[1], hi[2], hi[3]));
        o.z = med3(max3(lo[2], lo[3], lo[4]),
                   med3(mi[2], mi[3], mi[4]),
                   min3(hi[2], hi[3], hi[4]));
        o.w = med3(max3(lo[3], lo[4], lo[5]),
                   med3(mi[3], mi[4], mi[5]),
                   min3(hi[3], hi[4], hi[5]));

        float* po = oplane + (size_t)(h0 + i) * W + c0;
        __builtin_nontemporal_store(o, reinterpret_cast<vf4*>(po));
    }
}

extern "C" void kernel_launch(void* const* d_in, const int* in_sizes, int n_in,
                              void* d_out, int out_size, void* d_ws, size_t ws_size,
                              hipStream_t stream) {
    const float* x = (const float*)d_in[0];
    float* out = (float*)d_out;
    // 16*3 planes * 64 row-blocks * 128 groups = 393,216 threads -> 1536 blocks
    constexpr int threads = 256;
    constexpr int total = 16 * 3 * (512 / ROWS) * (512 / 4);
    median_blur_kernel<<<total / threads, threads, 0, stream>>>(x, out);
}